// Round 3
// baseline (465.823 us; speedup 1.0000x reference)
//
#include <hip/hip_runtime.h>
#include <math.h>

#define T_LEN 512
#define B_N   1024
#define K_N   48
#define START_TAG (K_N - 2)
#define STOP_TAG  (K_N - 1)
#define NEG   -10000.0f

// One wave (64 threads) per batch; lane j owns state j (row j of E = exp(trans)).
// Scaled-exponential domain: q_j = exp(alpha_j - C).
//   s_j  = sum_{k<47} E[j,k] * q_k        (col 47 = STOP is exp(-1e4) = 0)
//   q'_j = F_j * inv * s_j,  F_j = exp(feat[t,b,j]), inv = 1/q_0, C += log(q_0)
// The q broadcast is 47 v_readlane -> SGPRs (no LDS, no barrier, no memory
// in the recursion). E is held in 47 *named* float registers — R1/R2 showed
// (VGPR_Count=48) that a float[48] array was never promoted and lived in
// scratch, which was the real bottleneck.

#define REP47(M) M(0)M(1)M(2)M(3)M(4)M(5)M(6)M(7)M(8)M(9)M(10)M(11)M(12) \
  M(13)M(14)M(15)M(16)M(17)M(18)M(19)M(20)M(21)M(22)M(23)M(24)M(25)M(26) \
  M(27)M(28)M(29)M(30)M(31)M(32)M(33)M(34)M(35)M(36)M(37)M(38)M(39)M(40) \
  M(41)M(42)M(43)M(44)M(45)M(46)

__global__ __launch_bounds__(64) void crf_fused_kernel(
    const float* __restrict__ feats,    // (T, B, K)
    const float* __restrict__ trans,    // (K, K)
    const int*   __restrict__ tags,     // (B, T)
    const int*   __restrict__ lengths,  // (B,)
    float* __restrict__ out)
{
    const int b    = blockIdx.x;
    const int lane = threadIdx.x;
    const int len  = lengths[b];

    // E row j in named scalars (guaranteed VGPR promotion).
    // Lanes >= K_N: zeros, so their q stays 0 and is never readlane'd.
#define DECL_E(k) float E##k = (lane < K_N) ? __expf(trans[lane * K_N + k]) : 0.0f;
    REP47(DECL_E)
#undef DECL_E

    const float*  fb = feats + (size_t)b * K_N;
    const size_t  sT = (size_t)B_N * K_N;

    float q = (lane == START_TAG) ? 1.0f : 0.0f;
    float C = 0.0f;

    // Distance-4 raw-feat prefetch pipeline.
    float F_cur = __expf((lane < K_N) ? fb[lane] : 0.0f);
    float r1 = (1 < len && lane < K_N) ? fb[sT + lane]     : 0.0f;
    float r2 = (2 < len && lane < K_N) ? fb[2 * sT + lane] : 0.0f;
    float r3 = (3 < len && lane < K_N) ? fb[3 * sT + lane] : 0.0f;

    for (int t = 0; t < len; ++t) {
        // Broadcast q to wave-uniform values (SGPRs) via readlane.
#define DECL_S(k) float s##k = __uint_as_float(__builtin_amdgcn_readlane(__float_as_uint(q), k));
        REP47(DECL_S)
#undef DECL_S

        // Off-chain scalar work (overlaps with the FMA dot below).
        float inv, dC;
        if (s0 > 0.0f) { inv = 1.0f / s0; dC = __logf(s0); }  // false only at t==0
        else           { inv = 1.0f;      dC = 0.0f; }
        C += dC;
        float scale  = F_cur * inv;
        F_cur = __expf(r1);
        float rload = (t + 4 < len && lane < K_N) ? fb[(size_t)(t + 4) * sT + lane] : 0.0f;

        // 47-term dot, 4 accumulator chains.
        float a0 = 0.f, a1 = 0.f, a2 = 0.f, a3 = 0.f;
#define FMA4(k0,k1,k2,k3) \
        a0 = fmaf(E##k0, s##k0, a0); a1 = fmaf(E##k1, s##k1, a1); \
        a2 = fmaf(E##k2, s##k2, a2); a3 = fmaf(E##k3, s##k3, a3);
        FMA4(0,1,2,3)    FMA4(4,5,6,7)    FMA4(8,9,10,11)  FMA4(12,13,14,15)
        FMA4(16,17,18,19) FMA4(20,21,22,23) FMA4(24,25,26,27) FMA4(28,29,30,31)
        FMA4(32,33,34,35) FMA4(36,37,38,39) FMA4(40,41,42,43)
        a0 = fmaf(E44, s44, a0); a1 = fmaf(E45, s45, a1); a2 = fmaf(E46, s46, a2);
#undef FMA4
        float s = (a0 + a1) + (a2 + a3);

        q = s * scale;
        r1 = r2; r2 = r3; r3 = rload;
    }

    // log_z = C + log(q_j) + trans[STOP, j], logsumexp over lanes.
    float v = (lane < K_N && q > 0.0f)
            ? C + __logf(q) + trans[STOP_TAG * K_N + lane] : -INFINITY;
    float mz = v;
    #pragma unroll
    for (int off = 32; off >= 1; off >>= 1)
        mz = fmaxf(mz, __shfl_xor(mz, off));
    float e = __expf(v - mz);
    float se = e;
    #pragma unroll
    for (int off = 32; off >= 1; off >>= 1)
        se += __shfl_xor(se, off);
    float log_z = mz + __logf(se);

    // Gold path score: lanes stripe over t.
    float gsum = 0.0f;
    for (int t = lane; t < len; t += 64) {
        int next = tags[(size_t)b * T_LEN + t];
        int prev = (t == 0) ? START_TAG : tags[(size_t)b * T_LEN + t - 1];
        gsum += trans[next * K_N + prev]
              + fb[(size_t)t * sT + next];
    }
    #pragma unroll
    for (int off = 32; off >= 1; off >>= 1)
        gsum += __shfl_xor(gsum, off);

    if (lane == 0) {
        int last = tags[(size_t)b * T_LEN + len - 1];
        float gold = gsum + trans[STOP_TAG * K_N + last];
        atomicAdd(out, log_z - gold);
    }
}

extern "C" void kernel_launch(void* const* d_in, const int* in_sizes, int n_in,
                              void* d_out, int out_size, void* d_ws, size_t ws_size,
                              hipStream_t stream) {
    const float* feats   = (const float*)d_in[0];
    const float* trans   = (const float*)d_in[1];
    const int*   tags    = (const int*)d_in[2];
    const int*   lengths = (const int*)d_in[3];
    float* out = (float*)d_out;

    hipMemsetAsync(out, 0, sizeof(float) * out_size, stream);
    crf_fused_kernel<<<B_N, 64, 0, stream>>>(feats, trans, tags, lengths, out);
}